// Round 7
// baseline (1077.398 us; speedup 1.0000x reference)
//
#include <hip/hip_runtime.h>

#define B_   128
#define T_   16

typedef __bf16 bf16;
typedef __bf16 bf16x8 __attribute__((ext_vector_type(8)));
typedef float f32x4 __attribute__((ext_vector_type(4)));

#define GLL(SRC, DST) __builtin_amdgcn_global_load_lds( \
    (const __attribute__((address_space(1))) void*)(SRC), \
    (__attribute__((address_space(3))) void*)(DST), 16, 0, 0)

#define MFMA __builtin_amdgcn_mfma_f32_16x16x32_bf16

__device__ __forceinline__ float sigf(float x) { return 1.f / (1.f + expf(-x)); }

// ---------------------------------------------------------------------------
// Split-K GEMM, partials only. Tile 128x128, BK=64, DOUBLE-buffered LDS
// (R2-proven issue order: barrier -> stage next -> compute current).
// part slice layout: part + (zz*gridDim.x + nt)*16384, row-major 128x128.
// ---------------------------------------------------------------------------
__global__ __launch_bounds__(256) void gemm_k(
    const bf16* __restrict__ A, int lda,
    const bf16* __restrict__ W, int ldw, int Kc,
    float* __restrict__ part)
{
    __shared__ bf16 As[2][8192];
    __shared__ bf16 Bs[2][8192];

    const int nt = blockIdx.x, zz = blockIdx.y;
    const int tid = threadIdx.x, lane = tid & 63, wave = tid >> 6;
    const bf16* Ab = A + (size_t)zz * Kc;
    const bf16* Wb = W + (size_t)nt * 128 * ldw + (size_t)zz * Kc;

    const int srow = lane >> 3;
    const int scol = ((lane & 7) ^ srow) << 3;

    f32x4 acc[4][4];
#pragma unroll
    for (int m = 0; m < 4; ++m)
#pragma unroll
        for (int n = 0; n < 4; ++n) acc[m][n] = (f32x4){0.f, 0.f, 0.f, 0.f};

    const int wm = wave & 1, wn = wave >> 1;
    const int ln = lane & 15;
    const int rA = wm * 64 + ln;
    const int rB = wn * 64 + ln;
    const int swz = (lane & 7) << 4;
    const int kq  = (lane >> 4) << 4;

    auto stage = [&](int b, int koff) {
#pragma unroll
        for (int i = 0; i < 4; ++i) {
            int rb = i * 32 + wave * 8;
            GLL(Ab + (size_t)(rb + srow) * lda + koff + scol, &As[b][rb * 64]);
            GLL(Wb + (size_t)(rb + srow) * ldw + koff + scol, &Bs[b][rb * 64]);
        }
    };

    const int nk = Kc >> 6;
    stage(0, 0);
    int bq = 0;
    for (int it = 0; it < nk; ++it) {
        __syncthreads();
        if (it + 1 < nk) stage(bq ^ 1, (it + 1) << 6);
        const bf16* as = As[bq];
        const bf16* bs = Bs[bq];
#pragma unroll
        for (int k2 = 0; k2 < 2; ++k2) {
            const int co = (((k2 << 6) | kq) ^ swz) >> 1;
            bf16x8 a[4], b[4];
#pragma unroll
            for (int f = 0; f < 4; ++f) a[f] = *(const bf16x8*)&as[(rA + f * 16) * 64 + co];
#pragma unroll
            for (int f = 0; f < 4; ++f) b[f] = *(const bf16x8*)&bs[(rB + f * 16) * 64 + co];
#pragma unroll
            for (int m = 0; m < 4; ++m)
#pragma unroll
                for (int n = 0; n < 4; ++n)
                    acc[m][n] = MFMA(a[m], b[n], acc[m][n], 0, 0, 0);
        }
        bq ^= 1;
    }

    float* myp = part + ((size_t)(zz * gridDim.x + nt)) * 16384;
    const int q = lane >> 4;
#pragma unroll
    for (int m = 0; m < 4; ++m) {
        int row = wm * 64 + m * 16 + q * 4;
#pragma unroll
        for (int n = 0; n < 4; ++n) {
            int col = wn * 64 + n * 16 + ln;
#pragma unroll
            for (int r = 0; r < 4; ++r)
                myp[(size_t)(row + r) * 128 + col] = acc[m][n][r];
        }
    }
}

// ---------------------------------------------------------------------------
// kroles: 4 parallel skinny GEMMs (K=1024, tile 128x128, dbuf, XCD-swizzled).
//  role 0 (wr):  hdec @ Wwr^T   -> c_t += +b_wr; negs = -sig(c_t); opt out
//  role 1 (hd):  hdec @ Wd_e^T  -> hdPart fp32
//  role 2 (he):  henc @ We_e^T  -> hePart fp32
//  role 3 (dh):  hdec @ Wdh^T   -> gdhh fp32
// grid = 32 * nroles (nroles=4 in loop with role_add=0; 3 pre-loop role_add=1)
// ---------------------------------------------------------------------------
struct SmR { bf16 A[2][8192]; bf16 B[2][8192]; };  // 64 KB contiguous

__global__ __launch_bounds__(256) void kroles(
    const bf16* __restrict__ hdec, const bf16* __restrict__ henc,
    const bf16* __restrict__ Wwr,  const bf16* __restrict__ Wd_e,
    const bf16* __restrict__ We_e, const bf16* __restrict__ Wdh,
    float* __restrict__ c_t, bf16* __restrict__ negs,
    float* __restrict__ hdPart, float* __restrict__ hePart,
    float* __restrict__ gdhh, const float* __restrict__ b_wr,
    float* __restrict__ outp, int role_add)
{
    __shared__ SmR sm;
    const int q8 = gridDim.x >> 3;
    const int swzb = (blockIdx.x & 7) * q8 + (blockIdx.x >> 3);
    const int role = role_add + (swzb >> 5);
    const int nt = swzb & 31;

    const bf16* A = (role == 2) ? henc : hdec;
    const bf16* W = (role == 0) ? Wwr : (role == 1) ? Wd_e : (role == 2) ? We_e : Wdh;
    const bf16* Wb = W + (size_t)nt * 128 * 1024;

    const int tid = threadIdx.x, lane = tid & 63, wave = tid >> 6;
    const int srow = lane >> 3;
    const int scol = ((lane & 7) ^ srow) << 3;

    f32x4 acc[4][4];
#pragma unroll
    for (int m = 0; m < 4; ++m)
#pragma unroll
        for (int n = 0; n < 4; ++n) acc[m][n] = (f32x4){0.f, 0.f, 0.f, 0.f};

    const int wm = wave & 1, wn = wave >> 1;
    const int ln = lane & 15;
    const int rA = wm * 64 + ln;
    const int rB = wn * 64 + ln;
    const int swz = (lane & 7) << 4;
    const int kq  = (lane >> 4) << 4;

    auto stage = [&](int b, int koff) {
#pragma unroll
        for (int i = 0; i < 4; ++i) {
            int rb = i * 32 + wave * 8;
            GLL(A + (size_t)(rb + srow) * 1024 + koff + scol, &sm.A[b][rb * 64]);
            GLL(Wb + (size_t)(rb + srow) * 1024 + koff + scol, &sm.B[b][rb * 64]);
        }
    };

    stage(0, 0);
    int bq = 0;
    for (int it = 0; it < 16; ++it) {
        __syncthreads();
        if (it + 1 < 16) stage(bq ^ 1, (it + 1) << 6);
        const bf16* as = sm.A[bq];
        const bf16* bs = sm.B[bq];
#pragma unroll
        for (int k2 = 0; k2 < 2; ++k2) {
            const int co = (((k2 << 6) | kq) ^ swz) >> 1;
            bf16x8 a[4], b[4];
#pragma unroll
            for (int f = 0; f < 4; ++f) a[f] = *(const bf16x8*)&as[(rA + f * 16) * 64 + co];
#pragma unroll
            for (int f = 0; f < 4; ++f) b[f] = *(const bf16x8*)&bs[(rB + f * 16) * 64 + co];
#pragma unroll
            for (int m = 0; m < 4; ++m)
#pragma unroll
                for (int n = 0; n < 4; ++n)
                    acc[m][n] = MFMA(a[m], b[n], acc[m][n], 0, 0, 0);
        }
        bq ^= 1;
    }

    const int q = lane >> 4;
    if (role != 0) {
        float* Pout = (role == 1) ? hdPart : (role == 2) ? hePart : gdhh;
#pragma unroll
        for (int m = 0; m < 4; ++m) {
            int row = wm * 64 + m * 16 + q * 4;
#pragma unroll
            for (int n = 0; n < 4; ++n) {
                int col = nt * 128 + wn * 64 + n * 16 + ln;
#pragma unroll
                for (int r = 0; r < 4; ++r)
                    Pout[(size_t)(row + r) * 4096 + col] = acc[m][n][r];
            }
        }
        return;
    }

    // role 0: acc -> LDS fp32 128x128, then fused c_t / negs / out epilogue
    __syncthreads();
    float* Cl = (float*)&sm;
#pragma unroll
    for (int m = 0; m < 4; ++m) {
        int row = wm * 64 + m * 16 + q * 4;
#pragma unroll
        for (int n = 0; n < 4; ++n) {
            int col = wn * 64 + n * 16 + ln;
#pragma unroll
            for (int r = 0; r < 4; ++r)
                Cl[(row + r) * 128 + col] = acc[m][n][r];
        }
    }
    __syncthreads();
#pragma unroll
    for (int it = 0; it < 16; ++it) {
        int li = it * 256 + tid;
        int row = li >> 5, cq = li & 31;
        int n0 = nt * 128 + cq * 4;
        int ci = row * 4096 + n0;
        float4 cv = *(const float4*)(c_t + ci);
        float4 ac = *(const float4*)(Cl + row * 128 + cq * 4);
        float4 bw = *(const float4*)(b_wr + n0);
        float v0 = cv.x + ac.x + bw.x, v1 = cv.y + ac.y + bw.y;
        float v2 = cv.z + ac.z + bw.z, v3 = cv.w + ac.w + bw.w;
        *(float4*)(c_t + ci) = make_float4(v0, v1, v2, v3);
        negs[(size_t)row * 4096 + n0 + 0] = (bf16)(-sigf(v0));
        negs[(size_t)row * 4096 + n0 + 1] = (bf16)(-sigf(v1));
        negs[(size_t)row * 4096 + n0 + 2] = (bf16)(-sigf(v2));
        negs[(size_t)row * 4096 + n0 + 3] = (bf16)(-sigf(v3));
        if (outp) {
            *(float4*)(outp + ci) = make_float4(sigf(v0), sigf(v1), sigf(v2), sigf(v3));
        }
    }
}

// ---------------------------------------------------------------------------
// kB: fin — sum 8 negs-slices + base + hdPart + hePart -> enc LSTM -> h_enc.
// grid 512 x 256 (one task per gate-quad).
// ---------------------------------------------------------------------------
__global__ __launch_bounds__(256) void kB(
    const float* __restrict__ part, const float* __restrict__ base,
    const float* __restrict__ hdPart, const float* __restrict__ hePart,
    float* __restrict__ c_enc, bf16* __restrict__ henc)
{
    const int i = blockIdx.x * 256 + threadIdx.x;   // 0..131071
    const int row = i >> 10, j = i & 1023;
    const int nt = j >> 5, lc = (j & 31) << 2;
    const float* p0 = part + (size_t)nt * 16384 + (size_t)row * 128 + lc;
    float s0 = 0.f, s1 = 0.f, s2 = 0.f, s3 = 0.f;
#pragma unroll
    for (int z = 0; z < 8; ++z) {
        float4 p = *(const float4*)(p0 + (size_t)z * 524288);
        s0 += p.x; s1 += p.y; s2 += p.z; s3 += p.w;
    }
    const size_t nb = (size_t)row * 4096 + (j << 2);
    float4 bb = *(const float4*)(base + nb);
    float4 hd = *(const float4*)(hdPart + nb);
    float4 he = *(const float4*)(hePart + nb);
    float gi = s0 + bb.x + hd.x + he.x;
    float gf = s1 + bb.y + hd.y + he.y;
    float gg = s2 + bb.z + hd.z + he.z;
    float go = s3 + bb.w + hd.w + he.w;
    float cn = sigf(gf) * c_enc[i] + sigf(gi) * tanhf(gg);
    c_enc[i] = cn;
    henc[i] = (bf16)(sigf(go) * tanhf(cn));
}

// ---------------------------------------------------------------------------
// kC: mu/sigma GEMM (tile 128x32, K=1024 as 4x256) + reparam -> zbf. grid 16.
// ---------------------------------------------------------------------------
struct SmemG32 {
    bf16 As[4][128][64];   // 64 KB
    bf16 Ws[4][32][64];    // 16 KB
};

__global__ __launch_bounds__(256) void kC(
    const bf16* __restrict__ henc, const bf16* __restrict__ Wms,
    const float* __restrict__ b_mu, const float* __restrict__ b_sig,
    const float* __restrict__ eps_t, bf16* __restrict__ zbf)
{
    __shared__ SmemG32 sm;
    const int nt = blockIdx.x;
    const int tid = threadIdx.x, lane = tid & 63, wave = tid >> 6;
    const int srow = lane >> 3, scol = ((lane & 7) ^ srow) << 3;
    const int ln = lane & 15, kq = (lane >> 4) << 4;
    const int swz = (lane & 7) << 4;
    const int rA = wave * 32 + ln;
    const bf16* Wb = Wms + (size_t)nt * 32 * 1024;

    f32x4 acc[2][2];
#pragma unroll
    for (int m = 0; m < 2; ++m)
#pragma unroll
        for (int n = 0; n < 2; ++n) acc[m][n] = (f32x4){0.f, 0.f, 0.f, 0.f};

    for (int it = 0; it < 4; ++it) {
        if (it) __syncthreads();
        const int koff = it * 256;
#pragma unroll
        for (int kc = 0; kc < 4; ++kc) {
            const int kg = koff + kc * 64 + scol;
#pragma unroll
            for (int i = 0; i < 4; ++i) {
                int rb = i * 32 + wave * 8;
                GLL(henc + (size_t)(rb + srow) * 1024 + kg, &sm.As[kc][rb][0]);
            }
            GLL(Wb + (size_t)(wave * 8 + srow) * 1024 + kg, &sm.Ws[kc][wave * 8][0]);
        }
        __syncthreads();
#pragma unroll
        for (int kc = 0; kc < 4; ++kc)
#pragma unroll
            for (int k2 = 0; k2 < 2; ++k2) {
                const int co = (((k2 << 6) | kq) ^ swz) >> 1;
                bf16x8 a0 = *(const bf16x8*)&sm.As[kc][rA][co];
                bf16x8 a1 = *(const bf16x8*)&sm.As[kc][rA + 16][co];
                bf16x8 b0 = *(const bf16x8*)&sm.Ws[kc][ln][co];
                bf16x8 b1 = *(const bf16x8*)&sm.Ws[kc][ln + 16][co];
                acc[0][0] = MFMA(a0, b0, acc[0][0], 0, 0, 0);
                acc[0][1] = MFMA(a0, b1, acc[0][1], 0, 0, 0);
                acc[1][0] = MFMA(a1, b0, acc[1][0], 0, 0, 0);
                acc[1][1] = MFMA(a1, b1, acc[1][1], 0, 0, 0);
            }
    }
    __syncthreads();

    float* Cl = (float*)&sm;
    const int q = lane >> 4;
#pragma unroll
    for (int f = 0; f < 2; ++f)
#pragma unroll
        for (int n = 0; n < 2; ++n)
#pragma unroll
            for (int r = 0; r < 4; ++r)
                Cl[(wave * 32 + f * 16 + q * 4 + r) * 33 + n * 16 + ln] = acc[f][n][r];
    __syncthreads();

#pragma unroll
    for (int it = 0; it < 8; ++it) {
        int li = it * 256 + tid;
        int row = li >> 4, zl = li & 15;
        int zi = nt * 16 + zl;
        float mu = Cl[row * 33 + zl * 2]     + b_mu[zi];
        float ls = Cl[row * 33 + zl * 2 + 1] + b_sig[zi];
        float z = eps_t[row * 256 + zi] * expf(ls) + mu;
        zbf[(size_t)row * 256 + zi] = (bf16)z;
    }
}

// ---------------------------------------------------------------------------
// kD: dec z-part (K=256, one-shot) + gdhh + biases + LSTM -> h_dec. grid 64.
// ---------------------------------------------------------------------------
struct SmemD {
    bf16 As[4][128][64];   // 64 KB
    bf16 Ws[4][64][64];    // 32 KB
};

__global__ __launch_bounds__(256) void kD(
    const bf16* __restrict__ zbf, const bf16* __restrict__ Wdz,
    const float* __restrict__ gdhh,
    const float* __restrict__ b_ihd, const float* __restrict__ b_hhd,
    float* __restrict__ c_dec, bf16* __restrict__ hdec)
{
    __shared__ SmemD sm;
    const int nt = blockIdx.x;
    const int tid = threadIdx.x, lane = tid & 63, wave = tid >> 6;
    const int srow = lane >> 3, scol = ((lane & 7) ^ srow) << 3;
    const int ln = lane & 15, q = lane >> 4;
    const int kq = q << 4, swz = (lane & 7) << 4;
    const int wr = wave & 1, wc = wave >> 1;
    const bf16* Wb = Wdz + (size_t)nt * 64 * 256;

    f32x4 acc[4][2];
#pragma unroll
    for (int f = 0; f < 4; ++f)
#pragma unroll
        for (int n = 0; n < 2; ++n) acc[f][n] = (f32x4){0.f, 0.f, 0.f, 0.f};

#pragma unroll
    for (int kc = 0; kc < 4; ++kc) {
        const int kg = kc * 64 + scol;
#pragma unroll
        for (int i = 0; i < 4; ++i) {
            int rb = i * 32 + wave * 8;
            GLL(zbf + (size_t)(rb + srow) * 256 + kg, &sm.As[kc][rb][0]);
        }
#pragma unroll
        for (int i = 0; i < 2; ++i) {
            int rbw = i * 32 + wave * 8;
            GLL(Wb + (size_t)(rbw + srow) * 256 + kg, &sm.Ws[kc][rbw][0]);
        }
    }
    __syncthreads();
#pragma unroll
    for (int kc = 0; kc < 4; ++kc)
#pragma unroll
        for (int k2 = 0; k2 < 2; ++k2) {
            const int co = (((k2 << 6) | kq) ^ swz) >> 1;
            bf16x8 b0 = *(const bf16x8*)&sm.Ws[kc][wc * 32 + ln][co];
            bf16x8 b1 = *(const bf16x8*)&sm.Ws[kc][wc * 32 + ln + 16][co];
#pragma unroll
            for (int f = 0; f < 4; ++f) {
                bf16x8 a = *(const bf16x8*)&sm.As[kc][wr * 64 + f * 16 + ln][co];
                acc[f][0] = MFMA(a, b0, acc[f][0], 0, 0, 0);
                acc[f][1] = MFMA(a, b1, acc[f][1], 0, 0, 0);
            }
        }
    __syncthreads();

    float* Cl = (float*)&sm;
#pragma unroll
    for (int f = 0; f < 4; ++f)
#pragma unroll
        for (int n = 0; n < 2; ++n)
#pragma unroll
            for (int r = 0; r < 4; ++r)
                Cl[(wr * 64 + f * 16 + q * 4 + r) * 66 + wc * 32 + n * 16 + ln] = acc[f][n][r];
    __syncthreads();

#pragma unroll
    for (int it = 0; it < 8; ++it) {
        int li = it * 256 + tid;
        int row = li >> 4, jl = li & 15;
        int J = nt * 16 + jl;
        const float* cr = &Cl[row * 66 + jl * 4];
        const float* gr = &gdhh[(size_t)row * 4096 + nt * 64 + jl * 4];
        float gi = cr[0] + gr[0] + b_ihd[J]        + b_hhd[J];
        float gf = cr[1] + gr[1] + b_ihd[1024 + J] + b_hhd[1024 + J];
        float gg = cr[2] + gr[2] + b_ihd[2048 + J] + b_hhd[2048 + J];
        float go = cr[3] + gr[3] + b_ihd[3072 + J] + b_hhd[3072 + J];
        int ci = row * 1024 + J;
        float cn = sigf(gf) * c_dec[ci] + sigf(gi) * tanhf(gg);
        c_dec[ci] = cn;
        hdec[ci] = (bf16)(sigf(go) * tanhf(cn));
    }
}

// ---------------------------------------------------------------------------
// fin0: reduce 8 slices -> base (+ both enc biases). grid (32,4).
// ---------------------------------------------------------------------------
__global__ __launch_bounds__(256) void fin0_k(
    const float* __restrict__ part, float* __restrict__ base,
    const float* __restrict__ b1, const float* __restrict__ b2)
{
    const int nt = blockIdx.x, rb = blockIdx.y;
    const float* p0 = part + (size_t)nt * 16384;
#pragma unroll
    for (int it = 0; it < 4; ++it) {
        const int li = it * 256 + threadIdx.x;
        const int row = rb * 32 + (li >> 5);
        const int cq = li & 31;
        const int c0 = cq << 2;
        float s0 = 0.f, s1 = 0.f, s2 = 0.f, s3 = 0.f;
#pragma unroll
        for (int z = 0; z < 8; ++z) {
            float4 p = *(const float4*)(p0 + (size_t)z * 524288 + (size_t)row * 128 + c0);
            s0 += p.x; s1 += p.y; s2 += p.z; s3 += p.w;
        }
        int j = nt * 32 + cq;
        int nb = row * 4096 + nt * 128 + c0;
        base[nb + 0] = s0 + b1[j]        + b2[j];
        base[nb + 1] = s1 + b1[1024 + j] + b2[1024 + j];
        base[nb + 2] = s2 + b1[2048 + j] + b2[2048 + j];
        base[nb + 3] = s3 + b1[3072 + j] + b2[3072 + j];
    }
}

// ---------------- init + weight packing ----------------
#define PBL (B_ * 4096)
#define PBH (B_ * 1024)

__global__ void init_k(const float* __restrict__ x, const float* __restrict__ c0,
                       const float* __restrict__ h0e, const float* __restrict__ h0d,
                       float* __restrict__ c_t, float* __restrict__ c_enc,
                       float* __restrict__ c_dec, bf16* __restrict__ negs,
                       bf16* __restrict__ henc, bf16* __restrict__ hdec,
                       bf16* __restrict__ x_bf) {
    int i = blockIdx.x * 256 + threadIdx.x;
    if (i >= PBL) return;
    int n = i & 4095;
    float c = c0[n];
    c_t[i] = c;
    negs[i] = (bf16)(-sigf(c));
    x_bf[i] = (bf16)x[i];
    if (i < PBH) {
        int j = i & 1023;
        c_enc[i] = 0.f;
        c_dec[i] = 0.f;
        henc[i] = (bf16)h0e[j];
        hdec[i] = (bf16)h0d[j];
    }
}

__device__ __forceinline__ bf16x8 cvt8(const float* s) {
    float4 a = *(const float4*)s, b = *(const float4*)(s + 4);
    bf16x8 v = { (bf16)a.x, (bf16)a.y, (bf16)a.z, (bf16)a.w,
                 (bf16)b.x, (bf16)b.y, (bf16)b.z, (bf16)b.w };
    return v;
}

// np = 4j+g <-> n = g*1024+j.  Emits Wxh[np][4096], Wsum[np][4096],
// Wd_e[np][1024], We_e[np][1024].
__global__ void conv_es_k(const float* __restrict__ Wih, const float* __restrict__ Whh,
                          bf16* __restrict__ wxh, bf16* __restrict__ wsum,
                          bf16* __restrict__ wde, bf16* __restrict__ wee) {
    int id = blockIdx.x * 256 + threadIdx.x;
    if (id >= 4096 * 768) return;
    int np = id / 768, c = (id - np * 768) * 8;
    int n = ((np & 3) << 10) + (np >> 2);
    if (c < 4096) {
        const float* sx = Wih + (size_t)n * 9216 + c;
        const float* sh = sx + 4096;
        float4 a = *(const float4*)sh, b = *(const float4*)(sh + 4);
        float4 e = *(const float4*)sx, f = *(const float4*)(sx + 4);
        bf16x8 vh = { (bf16)a.x, (bf16)a.y, (bf16)a.z, (bf16)a.w,
                      (bf16)b.x, (bf16)b.y, (bf16)b.z, (bf16)b.w };
        bf16x8 vs = { (bf16)(a.x + e.x), (bf16)(a.y + e.y), (bf16)(a.z + e.z), (bf16)(a.w + e.w),
                      (bf16)(b.x + f.x), (bf16)(b.y + f.y), (bf16)(b.z + f.z), (bf16)(b.w + f.w) };
        *(bf16x8*)(wxh  + (size_t)np * 4096 + c) = vh;
        *(bf16x8*)(wsum + (size_t)np * 4096 + c) = vs;
    } else if (c < 5120) {
        *(bf16x8*)(wde + (size_t)np * 1024 + (c - 4096)) =
            cvt8(Wih + (size_t)n * 9216 + 8192 + (c - 4096));
    } else {
        *(bf16x8*)(wee + (size_t)np * 1024 + (c - 5120)) =
            cvt8(Whh + (size_t)n * 1024 + (c - 5120));
    }
}

// Wdz[np][256], Wdh[np][1024]
__global__ void conv_dec_k(const float* __restrict__ Wih, const float* __restrict__ Whh,
                           bf16* __restrict__ wdz, bf16* __restrict__ wdh) {
    int id = blockIdx.x * 256 + threadIdx.x;
    if (id >= 4096 * 160) return;
    int np = id / 160, c = (id - np * 160) * 8;
    int n = ((np & 3) << 10) + (np >> 2);
    if (c < 256)
        *(bf16x8*)(wdz + (size_t)np * 256 + c) = cvt8(Wih + (size_t)n * 256 + c);
    else
        *(bf16x8*)(wdh + (size_t)np * 1024 + (c - 256)) =
            cvt8(Whh + (size_t)n * 1024 + (c - 256));
}

// Wms[np][k]: np = 2*zi + s; s=0 -> Wmu[zi], s=1 -> Wsig[zi]
__global__ void conv_ms_k(const float* __restrict__ Wmu, const float* __restrict__ Wsig,
                          bf16* __restrict__ dst) {
    int id = blockIdx.x * 256 + threadIdx.x;
    if (id >= 512 * 128) return;
    int np = id >> 7, c = (id & 127) * 8;
    int zi = np >> 1;
    const float* src = ((np & 1) ? Wsig : Wmu) + (size_t)zi * 1024 + c;
    *(bf16x8*)(dst + (size_t)np * 1024 + c) = cvt8(src);
}

__global__ void conv_wr_k(const float* __restrict__ Wwr, bf16* __restrict__ dst) {
    int id = blockIdx.x * 256 + threadIdx.x;
    if (id >= 4096 * 128) return;
    *(bf16x8*)(dst + (size_t)id * 8) = cvt8(Wwr + (size_t)id * 8);
}

// ---------------- launch ----------------
extern "C" void kernel_launch(void* const* d_in, const int* in_sizes, int n_in,
                              void* d_out, int out_size, void* d_ws, size_t ws_size,
                              hipStream_t stream) {
    const float* x      = (const float*)d_in[0];
    const float* eps    = (const float*)d_in[1];
    const float* c0     = (const float*)d_in[2];
    const float* h0e    = (const float*)d_in[3];
    const float* h0d    = (const float*)d_in[4];
    const float* W_ih_e = (const float*)d_in[5];
    const float* b_ih_e = (const float*)d_in[6];
    const float* W_hh_e = (const float*)d_in[7];
    const float* b_hh_e = (const float*)d_in[8];
    const float* W_mu   = (const float*)d_in[9];
    const float* b_mu   = (const float*)d_in[10];
    const float* W_sig  = (const float*)d_in[11];
    const float* b_sig  = (const float*)d_in[12];
    const float* W_ih_d = (const float*)d_in[13];
    const float* b_ih_d = (const float*)d_in[14];
    const float* W_hh_d = (const float*)d_in[15];
    const float* b_hh_d = (const float*)d_in[16];
    const float* W_wr   = (const float*)d_in[17];
    const float* b_wr   = (const float*)d_in[18];
    float* out = (float*)d_out;

    float* f = (float*)d_ws;
    float* c_t    = f; f += 524288;
    float* base   = f; f += 524288;
    float* part   = f; f += (size_t)8 * 32 * 16384;   // 16 MB (z=8)
    float* c_enc  = f; f += 131072;
    float* c_dec  = f; f += 131072;
    float* gdhh   = f; f += 524288;
    float* hdPart = f; f += 524288;
    float* hePart = f; f += 524288;
    bf16* bp    = (bf16*)f;
    bf16* negs  = bp; bp += (size_t)B_ * 4096;
    bf16* henc  = bp; bp += (size_t)B_ * 1024;
    bf16* hdec  = bp; bp += (size_t)B_ * 1024;
    bf16* zbf   = bp; bp += (size_t)B_ * 256;
    bf16* x_bf  = bp; bp += (size_t)B_ * 4096;
    bf16* Wxh   = bp; bp += (size_t)4096 * 4096;
    bf16* Wsum  = bp; bp += (size_t)4096 * 4096;
    bf16* Wd_e  = bp; bp += (size_t)4096 * 1024;
    bf16* We_e  = bp; bp += (size_t)4096 * 1024;
    bf16* Wdz   = bp; bp += (size_t)4096 * 256;
    bf16* Wdh   = bp; bp += (size_t)4096 * 1024;
    bf16* Wms   = bp; bp += (size_t)512 * 1024;
    bf16* Wwr   = bp; bp += (size_t)4096 * 1024;

    dim3 blk(256);

    init_k<<<(PBL + 255) / 256, blk, 0, stream>>>(x, c0, h0e, h0d, c_t, c_enc, c_dec,
                                                  negs, henc, hdec, x_bf);
    conv_es_k<<<(4096 * 768 + 255) / 256, blk, 0, stream>>>(W_ih_e, W_hh_e,
                                                            Wxh, Wsum, Wd_e, We_e);
    conv_dec_k<<<(4096 * 160 + 255) / 256, blk, 0, stream>>>(W_ih_d, W_hh_d, Wdz, Wdh);
    conv_ms_k<<<(512 * 128 + 255) / 256, blk, 0, stream>>>(W_mu, W_sig, Wms);
    conv_wr_k<<<(4096 * 128 + 255) / 256, blk, 0, stream>>>(W_wr, Wwr);

    // base = b_ih_e + b_hh_e + x @ Wsum^T  (gate-permuted), z=8
    gemm_k<<<dim3(32, 8), blk, 0, stream>>>(x_bf, 4096, Wsum, 4096, 512, part);
    fin0_k<<<dim3(32, 4), blk, 0, stream>>>(part, base, b_ih_e, b_hh_e);

    // pre-loop: hdPart/hePart/gdhh from initial h_dec, h_enc (roles 1..3)
    kroles<<<dim3(96), blk, 0, stream>>>(hdec, henc, Wwr, Wd_e, We_e, Wdh,
        c_t, negs, hdPart, hePart, gdhh, b_wr, nullptr, 1);

    for (int t = 0; t < T_; ++t) {
        // kA: negs @ Wxh^T (K=4096), z=8 -> part
        gemm_k<<<dim3(32, 8), blk, 0, stream>>>(negs, 4096, Wxh, 4096, 512, part);
        // kB: fin (8 slices + base + hdPart + hePart) + enc LSTM -> henc
        kB<<<dim3(512), blk, 0, stream>>>(part, base, hdPart, hePart, c_enc, henc);
        // kC: mu/sigma + reparam -> zbf
        kC<<<dim3(16), blk, 0, stream>>>(henc, Wms, b_mu, b_sig,
                                         eps + (size_t)t * (B_ * 256), zbf);
        // kD: dec z-part + gdhh + LSTM -> hdec
        kD<<<dim3(64), blk, 0, stream>>>(zbf, Wdz, gdhh, b_ih_d, b_hh_d, c_dec, hdec);
        // kE: wr (c_t,negs,out) || hdPart || hePart || gdhh for next step
        kroles<<<dim3(128), blk, 0, stream>>>(hdec, henc, Wwr, Wd_e, We_e, Wdh,
            c_t, negs, hdPart, hePart, gdhh, b_wr,
            (t == T_ - 1) ? out : nullptr, 0);
    }
}

// Round 8
// 1071.674 us; speedup vs baseline: 1.0053x; 1.0053x over previous
//
#include <hip/hip_runtime.h>

#define B_   128
#define T_   16

typedef __bf16 bf16;
typedef __bf16 bf16x8 __attribute__((ext_vector_type(8)));
typedef float f32x4 __attribute__((ext_vector_type(4)));

#define GLL(SRC, DST) __builtin_amdgcn_global_load_lds( \
    (const __attribute__((address_space(1))) void*)(SRC), \
    (__attribute__((address_space(3))) void*)(DST), 16, 0, 0)

#define MFMA __builtin_amdgcn_mfma_f32_16x16x32_bf16

__device__ __forceinline__ float sigf(float x) { return 1.f / (1.f + expf(-x)); }

// ---------------------------------------------------------------------------
// Split-K GEMM, partials only. Tile 128x128, BK=64, DOUBLE-buffered LDS
// (R2-proven issue order: barrier -> stage next -> compute current).
// part slice layout: part + (zz*gridDim.x + nt)*16384, row-major 128x128.
// ---------------------------------------------------------------------------
__global__ __launch_bounds__(256) void gemm_k(
    const bf16* __restrict__ A, int lda,
    const bf16* __restrict__ W, int ldw, int Kc,
    float* __restrict__ part)
{
    __shared__ bf16 As[2][8192];
    __shared__ bf16 Bs[2][8192];

    const int nt = blockIdx.x, zz = blockIdx.y;
    const int tid = threadIdx.x, lane = tid & 63, wave = tid >> 6;
    const bf16* Ab = A + (size_t)zz * Kc;
    const bf16* Wb = W + (size_t)nt * 128 * ldw + (size_t)zz * Kc;

    const int srow = lane >> 3;
    const int scol = ((lane & 7) ^ srow) << 3;

    f32x4 acc[4][4];
#pragma unroll
    for (int m = 0; m < 4; ++m)
#pragma unroll
        for (int n = 0; n < 4; ++n) acc[m][n] = (f32x4){0.f, 0.f, 0.f, 0.f};

    const int wm = wave & 1, wn = wave >> 1;
    const int ln = lane & 15;
    const int rA = wm * 64 + ln;
    const int rB = wn * 64 + ln;
    const int swz = (lane & 7) << 4;
    const int kq  = (lane >> 4) << 4;

    auto stage = [&](int b, int koff) {
#pragma unroll
        for (int i = 0; i < 4; ++i) {
            int rb = i * 32 + wave * 8;
            GLL(Ab + (size_t)(rb + srow) * lda + koff + scol, &As[b][rb * 64]);
            GLL(Wb + (size_t)(rb + srow) * ldw + koff + scol, &Bs[b][rb * 64]);
        }
    };

    const int nk = Kc >> 6;
    stage(0, 0);
    int bq = 0;
    for (int it = 0; it < nk; ++it) {
        __syncthreads();
        if (it + 1 < nk) stage(bq ^ 1, (it + 1) << 6);
        const bf16* as = As[bq];
        const bf16* bs = Bs[bq];
#pragma unroll
        for (int k2 = 0; k2 < 2; ++k2) {
            const int co = (((k2 << 6) | kq) ^ swz) >> 1;
            bf16x8 a[4], b[4];
#pragma unroll
            for (int f = 0; f < 4; ++f) a[f] = *(const bf16x8*)&as[(rA + f * 16) * 64 + co];
#pragma unroll
            for (int f = 0; f < 4; ++f) b[f] = *(const bf16x8*)&bs[(rB + f * 16) * 64 + co];
#pragma unroll
            for (int m = 0; m < 4; ++m)
#pragma unroll
                for (int n = 0; n < 4; ++n)
                    acc[m][n] = MFMA(a[m], b[n], acc[m][n], 0, 0, 0);
        }
        bq ^= 1;
    }

    float* myp = part + ((size_t)(zz * gridDim.x + nt)) * 16384;
    const int q = lane >> 4;
#pragma unroll
    for (int m = 0; m < 4; ++m) {
        int row = wm * 64 + m * 16 + q * 4;
#pragma unroll
        for (int n = 0; n < 4; ++n) {
            int col = wn * 64 + n * 16 + ln;
#pragma unroll
            for (int r = 0; r < 4; ++r)
                myp[(size_t)(row + r) * 128 + col] = acc[m][n][r];
        }
    }
}

// ---------------------------------------------------------------------------
// kroles: 4 parallel skinny GEMMs (K=1024, tile 128x128, dbuf, XCD-swizzled).
//  role 0 (wr):  hdec @ Wwr^T   -> c_t += +b_wr; negs = -sig(c_t); opt out
//  role 1 (hd):  hdec @ Wd_e^T  -> hdPart fp32
//  role 2 (he):  henc @ We_e^T  -> hePart fp32
//  role 3 (dh):  hdec @ Wdh^T   -> gdhh fp32
// grid = 32 * nroles (nroles=4 in loop with role_add=0; 3 pre-loop role_add=1)
// ---------------------------------------------------------------------------
struct SmR { bf16 A[2][8192]; bf16 B[2][8192]; };  // 64 KB contiguous

__global__ __launch_bounds__(256) void kroles(
    const bf16* __restrict__ hdec, const bf16* __restrict__ henc,
    const bf16* __restrict__ Wwr,  const bf16* __restrict__ Wd_e,
    const bf16* __restrict__ We_e, const bf16* __restrict__ Wdh,
    float* __restrict__ c_t, bf16* __restrict__ negs,
    float* __restrict__ hdPart, float* __restrict__ hePart,
    float* __restrict__ gdhh, const float* __restrict__ b_wr,
    float* __restrict__ outp, int role_add)
{
    __shared__ SmR sm;
    const int q8 = gridDim.x >> 3;
    const int swzb = (blockIdx.x & 7) * q8 + (blockIdx.x >> 3);
    const int role = role_add + (swzb >> 5);
    const int nt = swzb & 31;

    const bf16* A = (role == 2) ? henc : hdec;
    const bf16* W = (role == 0) ? Wwr : (role == 1) ? Wd_e : (role == 2) ? We_e : Wdh;
    const bf16* Wb = W + (size_t)nt * 128 * 1024;

    const int tid = threadIdx.x, lane = tid & 63, wave = tid >> 6;
    const int srow = lane >> 3;
    const int scol = ((lane & 7) ^ srow) << 3;

    f32x4 acc[4][4];
#pragma unroll
    for (int m = 0; m < 4; ++m)
#pragma unroll
        for (int n = 0; n < 4; ++n) acc[m][n] = (f32x4){0.f, 0.f, 0.f, 0.f};

    const int wm = wave & 1, wn = wave >> 1;
    const int ln = lane & 15;
    const int rA = wm * 64 + ln;
    const int rB = wn * 64 + ln;
    const int swz = (lane & 7) << 4;
    const int kq  = (lane >> 4) << 4;

    auto stage = [&](int b, int koff) {
#pragma unroll
        for (int i = 0; i < 4; ++i) {
            int rb = i * 32 + wave * 8;
            GLL(A + (size_t)(rb + srow) * 1024 + koff + scol, &sm.A[b][rb * 64]);
            GLL(Wb + (size_t)(rb + srow) * 1024 + koff + scol, &sm.B[b][rb * 64]);
        }
    };

    stage(0, 0);
    int bq = 0;
    for (int it = 0; it < 16; ++it) {
        __syncthreads();
        if (it + 1 < 16) stage(bq ^ 1, (it + 1) << 6);
        const bf16* as = sm.A[bq];
        const bf16* bs = sm.B[bq];
#pragma unroll
        for (int k2 = 0; k2 < 2; ++k2) {
            const int co = (((k2 << 6) | kq) ^ swz) >> 1;
            bf16x8 a[4], b[4];
#pragma unroll
            for (int f = 0; f < 4; ++f) a[f] = *(const bf16x8*)&as[(rA + f * 16) * 64 + co];
#pragma unroll
            for (int f = 0; f < 4; ++f) b[f] = *(const bf16x8*)&bs[(rB + f * 16) * 64 + co];
#pragma unroll
            for (int m = 0; m < 4; ++m)
#pragma unroll
                for (int n = 0; n < 4; ++n)
                    acc[m][n] = MFMA(a[m], b[n], acc[m][n], 0, 0, 0);
        }
        bq ^= 1;
    }

    const int q = lane >> 4;
    if (role != 0) {
        float* Pout = (role == 1) ? hdPart : (role == 2) ? hePart : gdhh;
#pragma unroll
        for (int m = 0; m < 4; ++m) {
            int row = wm * 64 + m * 16 + q * 4;
#pragma unroll
            for (int n = 0; n < 4; ++n) {
                int col = nt * 128 + wn * 64 + n * 16 + ln;
#pragma unroll
                for (int r = 0; r < 4; ++r)
                    Pout[(size_t)(row + r) * 4096 + col] = acc[m][n][r];
            }
        }
        return;
    }

    // role 0: acc -> LDS fp32 128x128, then fused c_t / negs / out epilogue
    __syncthreads();
    float* Cl = (float*)&sm;
#pragma unroll
    for (int m = 0; m < 4; ++m) {
        int row = wm * 64 + m * 16 + q * 4;
#pragma unroll
        for (int n = 0; n < 4; ++n) {
            int col = wn * 64 + n * 16 + ln;
#pragma unroll
            for (int r = 0; r < 4; ++r)
                Cl[(row + r) * 128 + col] = acc[m][n][r];
        }
    }
    __syncthreads();
#pragma unroll
    for (int it = 0; it < 16; ++it) {
        int li = it * 256 + tid;
        int row = li >> 5, cq = li & 31;
        int n0 = nt * 128 + cq * 4;
        int ci = row * 4096 + n0;
        float4 cv = *(const float4*)(c_t + ci);
        float4 ac = *(const float4*)(Cl + row * 128 + cq * 4);
        float4 bw = *(const float4*)(b_wr + n0);
        float v0 = cv.x + ac.x + bw.x, v1 = cv.y + ac.y + bw.y;
        float v2 = cv.z + ac.z + bw.z, v3 = cv.w + ac.w + bw.w;
        *(float4*)(c_t + ci) = make_float4(v0, v1, v2, v3);
        negs[(size_t)row * 4096 + n0 + 0] = (bf16)(-sigf(v0));
        negs[(size_t)row * 4096 + n0 + 1] = (bf16)(-sigf(v1));
        negs[(size_t)row * 4096 + n0 + 2] = (bf16)(-sigf(v2));
        negs[(size_t)row * 4096 + n0 + 3] = (bf16)(-sigf(v3));
        if (outp) {
            *(float4*)(outp + ci) = make_float4(sigf(v0), sigf(v1), sigf(v2), sigf(v3));
        }
    }
}

// ---------------------------------------------------------------------------
// kB: fin — sum 8 negs-slices + base + hdPart + hePart -> enc LSTM -> h_enc.
// grid 512 x 256 (one task per gate-quad).
// ---------------------------------------------------------------------------
__global__ __launch_bounds__(256) void kB(
    const float* __restrict__ part, const float* __restrict__ base,
    const float* __restrict__ hdPart, const float* __restrict__ hePart,
    float* __restrict__ c_enc, bf16* __restrict__ henc)
{
    const int i = blockIdx.x * 256 + threadIdx.x;   // 0..131071
    const int row = i >> 10, j = i & 1023;
    const int nt = j >> 5, lc = (j & 31) << 2;
    const float* p0 = part + (size_t)nt * 16384 + (size_t)row * 128 + lc;
    float s0 = 0.f, s1 = 0.f, s2 = 0.f, s3 = 0.f;
#pragma unroll
    for (int z = 0; z < 8; ++z) {
        float4 p = *(const float4*)(p0 + (size_t)z * 524288);
        s0 += p.x; s1 += p.y; s2 += p.z; s3 += p.w;
    }
    const size_t nb = (size_t)row * 4096 + (j << 2);
    float4 bb = *(const float4*)(base + nb);
    float4 hd = *(const float4*)(hdPart + nb);
    float4 he = *(const float4*)(hePart + nb);
    float gi = s0 + bb.x + hd.x + he.x;
    float gf = s1 + bb.y + hd.y + he.y;
    float gg = s2 + bb.z + hd.z + he.z;
    float go = s3 + bb.w + hd.w + he.w;
    float cn = sigf(gf) * c_enc[i] + sigf(gi) * tanhf(gg);
    c_enc[i] = cn;
    henc[i] = (bf16)(sigf(go) * tanhf(cn));
}

// ---------------------------------------------------------------------------
// kC: mu/sigma GEMM (tile 128x32, K=1024 as 4x256) + reparam -> zbf. grid 16.
// ---------------------------------------------------------------------------
struct SmemG32 {
    bf16 As[4][128][64];   // 64 KB
    bf16 Ws[4][32][64];    // 16 KB
};

__global__ __launch_bounds__(256) void kC(
    const bf16* __restrict__ henc, const bf16* __restrict__ Wms,
    const float* __restrict__ b_mu, const float* __restrict__ b_sig,
    const float* __restrict__ eps_t, bf16* __restrict__ zbf)
{
    __shared__ SmemG32 sm;
    const int nt = blockIdx.x;
    const int tid = threadIdx.x, lane = tid & 63, wave = tid >> 6;
    const int srow = lane >> 3, scol = ((lane & 7) ^ srow) << 3;
    const int ln = lane & 15, kq = (lane >> 4) << 4;
    const int swz = (lane & 7) << 4;
    const int rA = wave * 32 + ln;
    const bf16* Wb = Wms + (size_t)nt * 32 * 1024;

    f32x4 acc[2][2];
#pragma unroll
    for (int m = 0; m < 2; ++m)
#pragma unroll
        for (int n = 0; n < 2; ++n) acc[m][n] = (f32x4){0.f, 0.f, 0.f, 0.f};

    for (int it = 0; it < 4; ++it) {
        if (it) __syncthreads();
        const int koff = it * 256;
#pragma unroll
        for (int kc = 0; kc < 4; ++kc) {
            const int kg = koff + kc * 64 + scol;
#pragma unroll
            for (int i = 0; i < 4; ++i) {
                int rb = i * 32 + wave * 8;
                GLL(henc + (size_t)(rb + srow) * 1024 + kg, &sm.As[kc][rb][0]);
            }
            GLL(Wb + (size_t)(wave * 8 + srow) * 1024 + kg, &sm.Ws[kc][wave * 8][0]);
        }
        __syncthreads();
#pragma unroll
        for (int kc = 0; kc < 4; ++kc)
#pragma unroll
            for (int k2 = 0; k2 < 2; ++k2) {
                const int co = (((k2 << 6) | kq) ^ swz) >> 1;
                bf16x8 a0 = *(const bf16x8*)&sm.As[kc][rA][co];
                bf16x8 a1 = *(const bf16x8*)&sm.As[kc][rA + 16][co];
                bf16x8 b0 = *(const bf16x8*)&sm.Ws[kc][ln][co];
                bf16x8 b1 = *(const bf16x8*)&sm.Ws[kc][ln + 16][co];
                acc[0][0] = MFMA(a0, b0, acc[0][0], 0, 0, 0);
                acc[0][1] = MFMA(a0, b1, acc[0][1], 0, 0, 0);
                acc[1][0] = MFMA(a1, b0, acc[1][0], 0, 0, 0);
                acc[1][1] = MFMA(a1, b1, acc[1][1], 0, 0, 0);
            }
    }
    __syncthreads();

    float* Cl = (float*)&sm;
    const int q = lane >> 4;
#pragma unroll
    for (int f = 0; f < 2; ++f)
#pragma unroll
        for (int n = 0; n < 2; ++n)
#pragma unroll
            for (int r = 0; r < 4; ++r)
                Cl[(wave * 32 + f * 16 + q * 4 + r) * 33 + n * 16 + ln] = acc[f][n][r];
    __syncthreads();

#pragma unroll
    for (int it = 0; it < 8; ++it) {
        int li = it * 256 + tid;
        int row = li >> 4, zl = li & 15;
        int zi = nt * 16 + zl;
        float mu = Cl[row * 33 + zl * 2]     + b_mu[zi];
        float ls = Cl[row * 33 + zl * 2 + 1] + b_sig[zi];
        float z = eps_t[row * 256 + zi] * expf(ls) + mu;
        zbf[(size_t)row * 256 + zi] = (bf16)z;
    }
}

// ---------------------------------------------------------------------------
// kD: dec z-part (K=256, one-shot) + gdhh + biases + LSTM -> h_dec. grid 64.
// ---------------------------------------------------------------------------
struct SmemD {
    bf16 As[4][128][64];   // 64 KB
    bf16 Ws[4][64][64];    // 32 KB
};

__global__ __launch_bounds__(256) void kD(
    const bf16* __restrict__ zbf, const bf16* __restrict__ Wdz,
    const float* __restrict__ gdhh,
    const float* __restrict__ b_ihd, const float* __restrict__ b_hhd,
    float* __restrict__ c_dec, bf16* __restrict__ hdec)
{
    __shared__ SmemD sm;
    const int nt = blockIdx.x;
    const int tid = threadIdx.x, lane = tid & 63, wave = tid >> 6;
    const int srow = lane >> 3, scol = ((lane & 7) ^ srow) << 3;
    const int ln = lane & 15, q = lane >> 4;
    const int kq = q << 4, swz = (lane & 7) << 4;
    const int wr = wave & 1, wc = wave >> 1;
    const bf16* Wb = Wdz + (size_t)nt * 64 * 256;

    f32x4 acc[4][2];
#pragma unroll
    for (int f = 0; f < 4; ++f)
#pragma unroll
        for (int n = 0; n < 2; ++n) acc[f][n] = (f32x4){0.f, 0.f, 0.f, 0.f};

#pragma unroll
    for (int kc = 0; kc < 4; ++kc) {
        const int kg = kc * 64 + scol;
#pragma unroll
        for (int i = 0; i < 4; ++i) {
            int rb = i * 32 + wave * 8;
            GLL(zbf + (size_t)(rb + srow) * 256 + kg, &sm.As[kc][rb][0]);
        }
#pragma unroll
        for (int i = 0; i < 2; ++i) {
            int rbw = i * 32 + wave * 8;
            GLL(Wb + (size_t)(rbw + srow) * 256 + kg, &sm.Ws[kc][rbw][0]);
        }
    }
    __syncthreads();
#pragma unroll
    for (int kc = 0; kc < 4; ++kc)
#pragma unroll
        for (int k2 = 0; k2 < 2; ++k2) {
            const int co = (((k2 << 6) | kq) ^ swz) >> 1;
            bf16x8 b0 = *(const bf16x8*)&sm.Ws[kc][wc * 32 + ln][co];
            bf16x8 b1 = *(const bf16x8*)&sm.Ws[kc][wc * 32 + ln + 16][co];
#pragma unroll
            for (int f = 0; f < 4; ++f) {
                bf16x8 a = *(const bf16x8*)&sm.As[kc][wr * 64 + f * 16 + ln][co];
                acc[f][0] = MFMA(a, b0, acc[f][0], 0, 0, 0);
                acc[f][1] = MFMA(a, b1, acc[f][1], 0, 0, 0);
            }
        }
    __syncthreads();

    float* Cl = (float*)&sm;
#pragma unroll
    for (int f = 0; f < 4; ++f)
#pragma unroll
        for (int n = 0; n < 2; ++n)
#pragma unroll
            for (int r = 0; r < 4; ++r)
                Cl[(wr * 64 + f * 16 + q * 4 + r) * 66 + wc * 32 + n * 16 + ln] = acc[f][n][r];
    __syncthreads();

#pragma unroll
    for (int it = 0; it < 8; ++it) {
        int li = it * 256 + tid;
        int row = li >> 4, jl = li & 15;
        int J = nt * 16 + jl;
        const float* cr = &Cl[row * 66 + jl * 4];
        const float* gr = &gdhh[(size_t)row * 4096 + nt * 64 + jl * 4];
        float gi = cr[0] + gr[0] + b_ihd[J]        + b_hhd[J];
        float gf = cr[1] + gr[1] + b_ihd[1024 + J] + b_hhd[1024 + J];
        float gg = cr[2] + gr[2] + b_ihd[2048 + J] + b_hhd[2048 + J];
        float go = cr[3] + gr[3] + b_ihd[3072 + J] + b_hhd[3072 + J];
        int ci = row * 1024 + J;
        float cn = sigf(gf) * c_dec[ci] + sigf(gi) * tanhf(gg);
        c_dec[ci] = cn;
        hdec[ci] = (bf16)(sigf(go) * tanhf(cn));
    }
}

// ---------------------------------------------------------------------------
// fin0: reduce 8 slices -> base (+ both enc biases). grid (32,4).
// ---------------------------------------------------------------------------
__global__ __launch_bounds__(256) void fin0_k(
    const float* __restrict__ part, float* __restrict__ base,
    const float* __restrict__ b1, const float* __restrict__ b2)
{
    const int nt = blockIdx.x, rb = blockIdx.y;
    const float* p0 = part + (size_t)nt * 16384;
#pragma unroll
    for (int it = 0; it < 4; ++it) {
        const int li = it * 256 + threadIdx.x;
        const int row = rb * 32 + (li >> 5);
        const int cq = li & 31;
        const int c0 = cq << 2;
        float s0 = 0.f, s1 = 0.f, s2 = 0.f, s3 = 0.f;
#pragma unroll
        for (int z = 0; z < 8; ++z) {
            float4 p = *(const float4*)(p0 + (size_t)z * 524288 + (size_t)row * 128 + c0);
            s0 += p.x; s1 += p.y; s2 += p.z; s3 += p.w;
        }
        int j = nt * 32 + cq;
        int nb = row * 4096 + nt * 128 + c0;
        base[nb + 0] = s0 + b1[j]        + b2[j];
        base[nb + 1] = s1 + b1[1024 + j] + b2[1024 + j];
        base[nb + 2] = s2 + b1[2048 + j] + b2[2048 + j];
        base[nb + 3] = s3 + b1[3072 + j] + b2[3072 + j];
    }
}

// ---------------- init + weight packing ----------------
#define PBL (B_ * 4096)
#define PBH (B_ * 1024)

__global__ void init_k(const float* __restrict__ x, const float* __restrict__ c0,
                       const float* __restrict__ h0e, const float* __restrict__ h0d,
                       float* __restrict__ c_t, float* __restrict__ c_enc,
                       float* __restrict__ c_dec, bf16* __restrict__ negs,
                       bf16* __restrict__ henc, bf16* __restrict__ hdec,
                       bf16* __restrict__ x_bf) {
    int i = blockIdx.x * 256 + threadIdx.x;
    if (i >= PBL) return;
    int n = i & 4095;
    float c = c0[n];
    c_t[i] = c;
    negs[i] = (bf16)(-sigf(c));
    x_bf[i] = (bf16)x[i];
    if (i < PBH) {
        int j = i & 1023;
        c_enc[i] = 0.f;
        c_dec[i] = 0.f;
        henc[i] = (bf16)h0e[j];
        hdec[i] = (bf16)h0d[j];
    }
}

__device__ __forceinline__ bf16x8 cvt8(const float* s) {
    float4 a = *(const float4*)s, b = *(const float4*)(s + 4);
    bf16x8 v = { (bf16)a.x, (bf16)a.y, (bf16)a.z, (bf16)a.w,
                 (bf16)b.x, (bf16)b.y, (bf16)b.z, (bf16)b.w };
    return v;
}

// np = 4j+g <-> n = g*1024+j.  Emits Wxh[np][4096], Wsum[np][4096],
// Wd_e[np][1024], We_e[np][1024].
__global__ void conv_es_k(const float* __restrict__ Wih, const float* __restrict__ Whh,
                          bf16* __restrict__ wxh, bf16* __restrict__ wsum,
                          bf16* __restrict__ wde, bf16* __restrict__ wee) {
    int id = blockIdx.x * 256 + threadIdx.x;
    if (id >= 4096 * 768) return;
    int np = id / 768, c = (id - np * 768) * 8;
    int n = ((np & 3) << 10) + (np >> 2);
    if (c < 4096) {
        const float* sx = Wih + (size_t)n * 9216 + c;
        const float* sh = sx + 4096;
        float4 a = *(const float4*)sh, b = *(const float4*)(sh + 4);
        float4 e = *(const float4*)sx, f = *(const float4*)(sx + 4);
        bf16x8 vh = { (bf16)a.x, (bf16)a.y, (bf16)a.z, (bf16)a.w,
                      (bf16)b.x, (bf16)b.y, (bf16)b.z, (bf16)b.w };
        bf16x8 vs = { (bf16)(a.x + e.x), (bf16)(a.y + e.y), (bf16)(a.z + e.z), (bf16)(a.w + e.w),
                      (bf16)(b.x + f.x), (bf16)(b.y + f.y), (bf16)(b.z + f.z), (bf16)(b.w + f.w) };
        *(bf16x8*)(wxh  + (size_t)np * 4096 + c) = vh;
        *(bf16x8*)(wsum + (size_t)np * 4096 + c) = vs;
    } else if (c < 5120) {
        *(bf16x8*)(wde + (size_t)np * 1024 + (c - 4096)) =
            cvt8(Wih + (size_t)n * 9216 + 8192 + (c - 4096));
    } else {
        *(bf16x8*)(wee + (size_t)np * 1024 + (c - 5120)) =
            cvt8(Whh + (size_t)n * 1024 + (c - 5120));
    }
}

// Wdz[np][256], Wdh[np][1024]
__global__ void conv_dec_k(const float* __restrict__ Wih, const float* __restrict__ Whh,
                           bf16* __restrict__ wdz, bf16* __restrict__ wdh) {
    int id = blockIdx.x * 256 + threadIdx.x;
    if (id >= 4096 * 160) return;
    int np = id / 160, c = (id - np * 160) * 8;
    int n = ((np & 3) << 10) + (np >> 2);
    if (c < 256)
        *(bf16x8*)(wdz + (size_t)np * 256 + c) = cvt8(Wih + (size_t)n * 256 + c);
    else
        *(bf16x8*)(wdh + (size_t)np * 1024 + (c - 256)) =
            cvt8(Whh + (size_t)n * 1024 + (c - 256));
}

// Wms[np][k]: np = 2*zi + s; s=0 -> Wmu[zi], s=1 -> Wsig[zi]
__global__ void conv_ms_k(const float* __restrict__ Wmu, const float* __restrict__ Wsig,
                          bf16* __restrict__ dst) {
    int id = blockIdx.x * 256 + threadIdx.x;
    if (id >= 512 * 128) return;
    int np = id >> 7, c = (id & 127) * 8;
    int zi = np >> 1;
    const float* src = ((np & 1) ? Wsig : Wmu) + (size_t)zi * 1024 + c;
    *(bf16x8*)(dst + (size_t)np * 1024 + c) = cvt8(src);
}

__global__ void conv_wr_k(const float* __restrict__ Wwr, bf16* __restrict__ dst) {
    int id = blockIdx.x * 256 + threadIdx.x;
    if (id >= 4096 * 128) return;
    *(bf16x8*)(dst + (size_t)id * 8) = cvt8(Wwr + (size_t)id * 8);
}

// ---------------- launch ----------------
extern "C" void kernel_launch(void* const* d_in, const int* in_sizes, int n_in,
                              void* d_out, int out_size, void* d_ws, size_t ws_size,
                              hipStream_t stream) {
    const float* x      = (const float*)d_in[0];
    const float* eps    = (const float*)d_in[1];
    const float* c0     = (const float*)d_in[2];
    const float* h0e    = (const float*)d_in[3];
    const float* h0d    = (const float*)d_in[4];
    const float* W_ih_e = (const float*)d_in[5];
    const float* b_ih_e = (const float*)d_in[6];
    const float* W_hh_e = (const float*)d_in[7];
    const float* b_hh_e = (const float*)d_in[8];
    const float* W_mu   = (const float*)d_in[9];
    const float* b_mu   = (const float*)d_in[10];
    const float* W_sig  = (const float*)d_in[11];
    const float* b_sig  = (const float*)d_in[12];
    const float* W_ih_d = (const float*)d_in[13];
    const float* b_ih_d = (const float*)d_in[14];
    const float* W_hh_d = (const float*)d_in[15];
    const float* b_hh_d = (const float*)d_in[16];
    const float* W_wr   = (const float*)d_in[17];
    const float* b_wr   = (const float*)d_in[18];
    float* out = (float*)d_out;

    float* f = (float*)d_ws;
    float* c_t    = f; f += 524288;
    float* base   = f; f += 524288;
    float* part   = f; f += (size_t)8 * 32 * 16384;   // 16 MB (z=8)
    float* c_enc  = f; f += 131072;
    float* c_dec  = f; f += 131072;
    float* gdhh   = f; f += 524288;
    float* hdPart = f; f += 524288;
    float* hePart = f; f += 524288;
    bf16* bp    = (bf16*)f;
    bf16* negs  = bp; bp += (size_t)B_ * 4096;
    bf16* henc  = bp; bp += (size_t)B_ * 1024;
    bf16* hdec  = bp; bp += (size_t)B_ * 1024;
    bf16* zbf   = bp; bp += (size_t)B_ * 256;
    bf16* x_bf  = bp; bp += (size_t)B_ * 4096;
    bf16* Wxh   = bp; bp += (size_t)4096 * 4096;
    bf16* Wsum  = bp; bp += (size_t)4096 * 4096;
    bf16* Wd_e  = bp; bp += (size_t)4096 * 1024;
    bf16* We_e  = bp; bp += (size_t)4096 * 1024;
    bf16* Wdz   = bp; bp += (size_t)4096 * 256;
    bf16* Wdh   = bp; bp += (size_t)4096 * 1024;
    bf16* Wms   = bp; bp += (size_t)512 * 1024;
    bf16* Wwr   = bp; bp += (size_t)4096 * 1024;

    dim3 blk(256);

    init_k<<<(PBL + 255) / 256, blk, 0, stream>>>(x, c0, h0e, h0d, c_t, c_enc, c_dec,
                                                  negs, henc, hdec, x_bf);
    conv_es_k<<<(4096 * 768 + 255) / 256, blk, 0, stream>>>(W_ih_e, W_hh_e,
                                                            Wxh, Wsum, Wd_e, We_e);
    conv_dec_k<<<(4096 * 160 + 255) / 256, blk, 0, stream>>>(W_ih_d, W_hh_d, Wdz, Wdh);
    conv_ms_k<<<(512 * 128 + 255) / 256, blk, 0, stream>>>(W_mu, W_sig, Wms);
    conv_wr_k<<<(4096 * 128 + 255) / 256, blk, 0, stream>>>(W_wr, Wwr);

    // base = b_ih_e + b_hh_e + x @ Wsum^T  (gate-permuted), z=8
    gemm_k<<<dim3(32, 8), blk, 0, stream>>>(x_bf, 4096, Wsum, 4096, 512, part);
    fin0_k<<<dim3(32, 4), blk, 0, stream>>>(part, base, b_ih_e, b_hh_e);

    // pre-loop: hdPart/hePart/gdhh from initial h_dec, h_enc (roles 1..3)
    kroles<<<dim3(96), blk, 0, stream>>>(hdec, henc, Wwr, Wd_e, We_e, Wdh,
        c_t, negs, hdPart, hePart, gdhh, b_wr, nullptr, 1);

    for (int t = 0; t < T_; ++t) {
        // kA: negs @ Wxh^T (K=4096), z=8 -> part
        gemm_k<<<dim3(32, 8), blk, 0, stream>>>(negs, 4096, Wxh, 4096, 512, part);
        // kB: fin (8 slices + base + hdPart + hePart) + enc LSTM -> henc
        kB<<<dim3(512), blk, 0, stream>>>(part, base, hdPart, hePart, c_enc, henc);
        // kC: mu/sigma + reparam -> zbf
        kC<<<dim3(16), blk, 0, stream>>>(henc, Wms, b_mu, b_sig,
                                         eps + (size_t)t * (B_ * 256), zbf);
        // kD: dec z-part + gdhh + LSTM -> hdec
        kD<<<dim3(64), blk, 0, stream>>>(zbf, Wdz, gdhh, b_ih_d, b_hh_d, c_dec, hdec);
        // kE: wr (c_t,negs,out) || hdPart || hePart || gdhh for next step
        kroles<<<dim3(128), blk, 0, stream>>>(hdec, henc, Wwr, Wd_e, We_e, Wdh,
            c_t, negs, hdPart, hePart, gdhh, b_wr,
            (t == T_ - 1) ? out : nullptr, 0);
    }
}